// Round 3
// baseline (344.264 us; speedup 1.0000x reference)
//
#include <hip/hip_runtime.h>
#include <math.h>

#define NPTS 8192
#define TPB  128          // threads per block, pair kernels
#define QPL  2            // queries per lane
#define QPB  (TPB * QPL)  // 256 queries per block
#define TILE 128          // points staged per LDS tile (16 KB)
#define TPM  256          // threads per block, merge kernels

// ---------------------------------------------------------------------------
// max3 helper: this exact pattern reliably forms v_max3_f32; fabsf on the
// operands folds into VOP3 abs input modifiers.
// ---------------------------------------------------------------------------
__device__ __forceinline__ float fmax3(float a, float b, float c) {
    return fmaxf(fmaxf(a, b), c);
}

// 32-input Chebyshev: 32 subs + 17 max3/max ops (abs folded at leaves).
__device__ __forceinline__ float cheb32(const float* __restrict__ q,
                                        const float* __restrict__ p) {
    float s[32];
    #pragma unroll
    for (int k = 0; k < 32; ++k) s[k] = q[k] - p[k];
    float m[11];
    #pragma unroll
    for (int i = 0; i < 10; ++i)
        m[i] = fmax3(fabsf(s[3*i]), fabsf(s[3*i+1]), fabsf(s[3*i+2]));
    m[10] = fmaxf(fabsf(s[30]), fabsf(s[31]));
    float n0 = fmax3(m[0], m[1], m[2]);
    float n1 = fmax3(m[3], m[4], m[5]);
    float n2 = fmax3(m[6], m[7], m[8]);
    float n3 = fmaxf(m[9], m[10]);
    return fmaxf(fmax3(n0, n1, n2), n3);
}

// 16-input Chebyshev: 16 subs + 8 max3/max ops.
__device__ __forceinline__ float cheb16(const float* __restrict__ q,
                                        const float* __restrict__ p) {
    float s[16];
    #pragma unroll
    for (int k = 0; k < 16; ++k) s[k] = q[k] - p[k];
    float m0 = fmax3(fabsf(s[0]),  fabsf(s[1]),  fabsf(s[2]));
    float m1 = fmax3(fabsf(s[3]),  fabsf(s[4]),  fabsf(s[5]));
    float m2 = fmax3(fabsf(s[6]),  fabsf(s[7]),  fabsf(s[8]));
    float m3 = fmax3(fabsf(s[9]),  fabsf(s[10]), fabsf(s[11]));
    float m4 = fmax3(fabsf(s[12]), fabsf(s[13]), fabsf(s[14]));
    float n0 = fmax3(m0, m1, m2);
    float n1 = fmax3(m3, m4, fabsf(s[15]));
    return fmaxf(n0, n1);
}

// Branchless sorted-descending top-4 insert (7 ops).
__device__ __forceinline__ void ins4(float d, float& t0, float& t1, float& t2, float& t3) {
    float n0 = fminf(t0, d);  t0 = fmaxf(t0, d);
    float n1 = fminf(t1, n0); t1 = fmaxf(t1, n0);
    float n2 = fminf(t2, n1); t2 = fmaxf(t2, n1);
    t3 = fmaxf(t3, n2);
}

__device__ double digamma_d(double x) {
    double r = 0.0;
    while (x < 6.0) { r -= 1.0 / x; x += 1.0; }
    double f = 1.0 / (x * x);
    double t = f * (1.0/12.0 - f * (1.0/120.0 - f * (1.0/252.0 - f * (1.0/240.0 - f * (1.0/132.0)))));
    return r + log(x) - 0.5 / x - t;
}

// Cooperative stage of TILE points (x:16 + y:16 floats) into LDS.
// Layout: pts4[pt*8 + c], c<4 = x float4s, c>=4 = y float4s.
__device__ __forceinline__ void stage_tile(
    float4* pts4, const float* __restrict__ x, const float* __restrict__ y, int jt)
{
    #pragma unroll
    for (int i = 0; i < (TILE * 8) / TPB; ++i) {
        int li = i * TPB + threadIdx.x;
        int pt = li >> 3, c = li & 7;
        const float4* src = (c < 4)
            ? reinterpret_cast<const float4*>(x) + (size_t)(jt + pt) * 4 + c
            : reinterpret_cast<const float4*>(y) + (size_t)(jt + pt) * 4 + (c - 4);
        pts4[li] = *src;
    }
}

__device__ __forceinline__ void load_query(float* qv, const float* __restrict__ x,
                                           const float* __restrict__ y, int q)
{
    const float4* qx4 = reinterpret_cast<const float4*>(x) + (size_t)q * 4;
    const float4* qy4 = reinterpret_cast<const float4*>(y) + (size_t)q * 4;
    #pragma unroll
    for (int i = 0; i < 4; ++i) {
        float4 v = qx4[i];
        qv[4*i+0] = v.x; qv[4*i+1] = v.y; qv[4*i+2] = v.z; qv[4*i+3] = v.w;
        float4 w = qy4[i];
        qv[16+4*i+0] = w.x; qv[16+4*i+1] = w.y; qv[16+4*i+2] = w.z; qv[16+4*i+3] = w.w;
    }
}

// ---------------------------------------------------------------------------
// K1: per-query partial top-4 of joint Chebyshev distance over a point split.
// grid = (NPTS/QPB, S); 2 queries per lane amortize each LDS point read.
// ---------------------------------------------------------------------------
__global__ __launch_bounds__(TPB) void knn_part_kernel(
    const float* __restrict__ x, const float* __restrict__ y,
    float4* __restrict__ part, int pps)
{
    __shared__ float4 pts4[TILE * 8];
    const int q0 = blockIdx.x * QPB + threadIdx.x;
    const int q1 = q0 + TPB;
    float qa[32], qb[32];
    load_query(qa, x, y, q0);
    load_query(qb, x, y, q1);

    float a0=-1.f,a1=-1.f,a2=-1.f,a3=-1.f;
    float b0=-1.f,b1=-1.f,b2=-1.f,b3=-1.f;

    const int j0 = blockIdx.y * pps;
    for (int jt = j0; jt < j0 + pps; jt += TILE) {
        stage_tile(pts4, x, y, jt);
        __syncthreads();
        #pragma unroll 2
        for (int jj = 0; jj < TILE; ++jj) {
            float p[32];
            #pragma unroll
            for (int i = 0; i < 8; ++i) {
                float4 v = pts4[jj * 8 + i];   // wave-uniform broadcast
                p[4*i+0] = v.x; p[4*i+1] = v.y; p[4*i+2] = v.z; p[4*i+3] = v.w;
            }
            ins4(cheb32(qa, p), a0, a1, a2, a3);
            ins4(cheb32(qb, p), b0, b1, b2, b3);
        }
        __syncthreads();
    }
    part[(size_t)blockIdx.y * NPTS + q0] = make_float4(a0, a1, a2, a3);
    part[(size_t)blockIdx.y * NPTS + q1] = make_float4(b0, b1, b2, b3);
}

// ---------------------------------------------------------------------------
// K2: merge S partial top-4 lists per query -> radius r[q]
// ---------------------------------------------------------------------------
__global__ __launch_bounds__(TPM) void knn_merge_kernel(
    const float4* __restrict__ part, float* __restrict__ r, int S)
{
    const int q = blockIdx.x * TPM + threadIdx.x;
    float t0=-1.f,t1=-1.f,t2=-1.f,t3=-1.f;
    for (int s = 0; s < S; ++s) {
        float4 v = part[(size_t)s * NPTS + q];
        ins4(v.x, t0, t1, t2, t3);
        ins4(v.y, t0, t1, t2, t3);
        ins4(v.z, t0, t1, t2, t3);
        ins4(v.w, t0, t1, t2, t3);
    }
    r[q] = t3 - 1e-15f;
}

// ---------------------------------------------------------------------------
// K3: partial inclusive range counts in X and Y marginals.
// ---------------------------------------------------------------------------
__global__ __launch_bounds__(TPB) void count_part_kernel(
    const float* __restrict__ x, const float* __restrict__ y,
    const float* __restrict__ r,
    int* __restrict__ cx, int* __restrict__ cy, int pps)
{
    __shared__ float4 pts4[TILE * 8];
    const int q0 = blockIdx.x * QPB + threadIdx.x;
    const int q1 = q0 + TPB;
    float qa[32], qb[32];
    load_query(qa, x, y, q0);
    load_query(qb, x, y, q1);
    const float ra = r[q0];
    const float rb = r[q1];

    int nxa = 0, nya = 0, nxb = 0, nyb = 0;

    const int j0 = blockIdx.y * pps;
    for (int jt = j0; jt < j0 + pps; jt += TILE) {
        stage_tile(pts4, x, y, jt);
        __syncthreads();
        #pragma unroll 2
        for (int jj = 0; jj < TILE; ++jj) {
            float p[32];
            #pragma unroll
            for (int i = 0; i < 8; ++i) {
                float4 v = pts4[jj * 8 + i];   // wave-uniform broadcast
                p[4*i+0] = v.x; p[4*i+1] = v.y; p[4*i+2] = v.z; p[4*i+3] = v.w;
            }
            nxa += (cheb16(qa,      p)      <= ra) ? 1 : 0;
            nya += (cheb16(qa + 16, p + 16) <= ra) ? 1 : 0;
            nxb += (cheb16(qb,      p)      <= rb) ? 1 : 0;
            nyb += (cheb16(qb + 16, p + 16) <= rb) ? 1 : 0;
        }
        __syncthreads();
    }
    cx[(size_t)blockIdx.y * NPTS + q0] = nxa;
    cy[(size_t)blockIdx.y * NPTS + q0] = nya;
    cx[(size_t)blockIdx.y * NPTS + q1] = nxb;
    cy[(size_t)blockIdx.y * NPTS + q1] = nyb;
}

// ---------------------------------------------------------------------------
// K4: merge partial counts -> digamma(nx)+digamma(ny) per query (f64).
// ---------------------------------------------------------------------------
__global__ __launch_bounds__(TPM) void count_merge_kernel(
    const int* __restrict__ cx, const int* __restrict__ cy,
    double* __restrict__ dig, int S)
{
    const int q = blockIdx.x * TPM + threadIdx.x;
    int nx = 0, ny = 0;
    for (int s = 0; s < S; ++s) {
        nx += cx[(size_t)s * NPTS + q];
        ny += cy[(size_t)s * NPTS + q];
    }
    dig[q] = digamma_d((double)nx) + digamma_d((double)ny);
}

// ---------------------------------------------------------------------------
// K5: ans = psi(N) + psi(k) - mean(psi(nx)+psi(ny))
// (log/log2 terms of the reference cancel exactly in ans_x+ans_y-ans_xy)
// ---------------------------------------------------------------------------
__global__ __launch_bounds__(TPM) void final_kernel(
    const double* __restrict__ dig, float* __restrict__ out)
{
    __shared__ double sm[TPM];
    double s = 0.0;
    for (int i = threadIdx.x; i < NPTS; i += TPM) s += dig[i];
    sm[threadIdx.x] = s;
    __syncthreads();
    for (int w = TPM / 2; w > 0; w >>= 1) {
        if (threadIdx.x < w) sm[threadIdx.x] += sm[threadIdx.x + w];
        __syncthreads();
    }
    if (threadIdx.x == 0) {
        double ans = digamma_d((double)NPTS) + digamma_d(4.0) - sm[0] / (double)NPTS;
        out[0] = (float)ans;
    }
}

// ---------------------------------------------------------------------------
extern "C" void kernel_launch(void* const* d_in, const int* in_sizes, int n_in,
                              void* d_out, int out_size, void* d_ws, size_t ws_size,
                              hipStream_t stream)
{
    (void)in_sizes; (void)n_in; (void)out_size;
    const float* x = (const float*)d_in[0];
    const float* y = (const float*)d_in[1];
    float* out = (float*)d_out;

    char* ws = (char*)d_ws;
    double* dig = (double*)ws;
    float*  r   = (float*)(ws + (size_t)NPTS * 8);
    char*   p0  = ws + (size_t)NPTS * 8 + (size_t)NPTS * 4;

    int S = 64;
    while (S > 1) {
        size_t need = (size_t)NPTS * 12 + (size_t)S * NPTS * 16 + (size_t)S * NPTS * 8;
        if (need <= ws_size) break;
        S >>= 1;
    }
    float4* part = (float4*)p0;
    int* cx = (int*)(p0 + (size_t)S * NPTS * 16);
    int* cy = cx + (size_t)S * NPTS;
    const int pps = NPTS / S;   // S<=64 -> pps>=128, multiple of TILE

    dim3 gridP(NPTS / QPB, S);
    knn_part_kernel<<<gridP, TPB, 0, stream>>>(x, y, part, pps);
    knn_merge_kernel<<<NPTS / TPM, TPM, 0, stream>>>(part, r, S);
    count_part_kernel<<<gridP, TPB, 0, stream>>>(x, y, r, cx, cy, pps);
    count_merge_kernel<<<NPTS / TPM, TPM, 0, stream>>>(cx, cy, dig, S);
    final_kernel<<<1, TPM, 0, stream>>>(dig, out);
}

// Round 4
// 276.974 us; speedup vs baseline: 1.2429x; 1.2429x over previous
//
#include <hip/hip_runtime.h>
#include <math.h>

#define NPTS 8192
#define TPB  256          // threads per block, pair kernels
#define TILE 64           // points staged per LDS tile (8 KB)
#define TPM  256          // threads per block, merge kernels

// ---------------------------------------------------------------------------
// max3 helper: folds to v_max3_f32 with abs input modifiers at the leaves.
// ---------------------------------------------------------------------------
__device__ __forceinline__ float fmax3(float a, float b, float c) {
    return fmaxf(fmaxf(a, b), c);
}

// 32-input Chebyshev: 32 subs + 17 max3/max ops (abs folded at leaves).
__device__ __forceinline__ float cheb32(const float* __restrict__ q,
                                        const float* __restrict__ p) {
    float s[32];
    #pragma unroll
    for (int k = 0; k < 32; ++k) s[k] = q[k] - p[k];
    float m[11];
    #pragma unroll
    for (int i = 0; i < 10; ++i)
        m[i] = fmax3(fabsf(s[3*i]), fabsf(s[3*i+1]), fabsf(s[3*i+2]));
    m[10] = fmaxf(fabsf(s[30]), fabsf(s[31]));
    float n0 = fmax3(m[0], m[1], m[2]);
    float n1 = fmax3(m[3], m[4], m[5]);
    float n2 = fmax3(m[6], m[7], m[8]);
    float n3 = fmaxf(m[9], m[10]);
    return fmaxf(fmax3(n0, n1, n2), n3);
}

// 16-input Chebyshev: 16 subs + 8 max3/max ops.
__device__ __forceinline__ float cheb16(const float* __restrict__ q,
                                        const float* __restrict__ p) {
    float s[16];
    #pragma unroll
    for (int k = 0; k < 16; ++k) s[k] = q[k] - p[k];
    float m0 = fmax3(fabsf(s[0]),  fabsf(s[1]),  fabsf(s[2]));
    float m1 = fmax3(fabsf(s[3]),  fabsf(s[4]),  fabsf(s[5]));
    float m2 = fmax3(fabsf(s[6]),  fabsf(s[7]),  fabsf(s[8]));
    float m3 = fmax3(fabsf(s[9]),  fabsf(s[10]), fabsf(s[11]));
    float m4 = fmax3(fabsf(s[12]), fabsf(s[13]), fabsf(s[14]));
    float n0 = fmax3(m0, m1, m2);
    float n1 = fmax3(m3, m4, fabsf(s[15]));
    return fmaxf(n0, n1);
}

// Branchless sorted-descending top-4 insert (7 ops).
__device__ __forceinline__ void ins4(float d, float& t0, float& t1, float& t2, float& t3) {
    float n0 = fminf(t0, d);  t0 = fmaxf(t0, d);
    float n1 = fminf(t1, n0); t1 = fmaxf(t1, n0);
    float n2 = fminf(t2, n1); t2 = fmaxf(t2, n1);
    t3 = fmaxf(t3, n2);
}

__device__ double digamma_d(double x) {
    double r = 0.0;
    while (x < 6.0) { r -= 1.0 / x; x += 1.0; }
    double f = 1.0 / (x * x);
    double t = f * (1.0/12.0 - f * (1.0/120.0 - f * (1.0/252.0 - f * (1.0/240.0 - f * (1.0/132.0)))));
    return r + log(x) - 0.5 / x - t;
}

// Cooperative stage of TILE points (x:16 + y:16 floats) into LDS.
// Layout: pts4[pt*8 + c], c<4 = x float4s, c>=4 = y float4s.
__device__ __forceinline__ void stage_tile(
    float4* pts4, const float* __restrict__ x, const float* __restrict__ y, int jt)
{
    #pragma unroll
    for (int i = 0; i < (TILE * 8) / TPB; ++i) {
        int li = i * TPB + threadIdx.x;
        int pt = li >> 3, c = li & 7;
        const float4* src = (c < 4)
            ? reinterpret_cast<const float4*>(x) + (size_t)(jt + pt) * 4 + c
            : reinterpret_cast<const float4*>(y) + (size_t)(jt + pt) * 4 + (c - 4);
        pts4[li] = *src;
    }
}

__device__ __forceinline__ void load_query(float* qv, const float* __restrict__ x,
                                           const float* __restrict__ y, int q)
{
    const float4* qx4 = reinterpret_cast<const float4*>(x) + (size_t)q * 4;
    const float4* qy4 = reinterpret_cast<const float4*>(y) + (size_t)q * 4;
    #pragma unroll
    for (int i = 0; i < 4; ++i) {
        float4 v = qx4[i];
        qv[4*i+0] = v.x; qv[4*i+1] = v.y; qv[4*i+2] = v.z; qv[4*i+3] = v.w;
        float4 w = qy4[i];
        qv[16+4*i+0] = w.x; qv[16+4*i+1] = w.y; qv[16+4*i+2] = w.z; qv[16+4*i+3] = w.w;
    }
}

// ---------------------------------------------------------------------------
// K1: per-query partial top-4 of joint Chebyshev distance over a point split.
// grid = (NPTS/(TPB*QPL), S); QPL queries/lane amortize LDS point reads.
// ---------------------------------------------------------------------------
template <int QPL>
__global__ __launch_bounds__(TPB) void knn_part_kernel(
    const float* __restrict__ x, const float* __restrict__ y,
    float4* __restrict__ part, int pps)
{
    __shared__ float4 pts4[TILE * 8];
    float qv[QPL][32];
    float t0[QPL], t1[QPL], t2[QPL], t3[QPL];
    #pragma unroll
    for (int u = 0; u < QPL; ++u) {
        load_query(qv[u], x, y, blockIdx.x * (TPB * QPL) + threadIdx.x + u * TPB);
        t0[u] = t1[u] = t2[u] = t3[u] = -1.0f;
    }

    const int j0 = blockIdx.y * pps;
    for (int jt = j0; jt < j0 + pps; jt += TILE) {
        stage_tile(pts4, x, y, jt);
        __syncthreads();
        #pragma unroll 2
        for (int jj = 0; jj < TILE; ++jj) {
            float p[32];
            #pragma unroll
            for (int i = 0; i < 8; ++i) {
                float4 v = pts4[jj * 8 + i];   // wave-uniform broadcast
                p[4*i+0] = v.x; p[4*i+1] = v.y; p[4*i+2] = v.z; p[4*i+3] = v.w;
            }
            #pragma unroll
            for (int u = 0; u < QPL; ++u)
                ins4(cheb32(qv[u], p), t0[u], t1[u], t2[u], t3[u]);
        }
        __syncthreads();
    }
    #pragma unroll
    for (int u = 0; u < QPL; ++u) {
        int q = blockIdx.x * (TPB * QPL) + threadIdx.x + u * TPB;
        part[(size_t)blockIdx.y * NPTS + q] = make_float4(t0[u], t1[u], t2[u], t3[u]);
    }
}

// ---------------------------------------------------------------------------
// K2: merge S partial top-4 lists per query -> radius r[q]
// ---------------------------------------------------------------------------
__global__ __launch_bounds__(TPM) void knn_merge_kernel(
    const float4* __restrict__ part, float* __restrict__ r, int S)
{
    const int q = blockIdx.x * TPM + threadIdx.x;
    float t0=-1.f,t1=-1.f,t2=-1.f,t3=-1.f;
    for (int s = 0; s < S; ++s) {
        float4 v = part[(size_t)s * NPTS + q];
        ins4(v.x, t0, t1, t2, t3);
        ins4(v.y, t0, t1, t2, t3);
        ins4(v.z, t0, t1, t2, t3);
        ins4(v.w, t0, t1, t2, t3);
    }
    r[q] = t3 - 1e-15f;
}

// ---------------------------------------------------------------------------
// K3: partial inclusive range counts in X and Y marginals.
// ---------------------------------------------------------------------------
template <int QPL>
__global__ __launch_bounds__(TPB) void count_part_kernel(
    const float* __restrict__ x, const float* __restrict__ y,
    const float* __restrict__ r,
    unsigned short* __restrict__ cx, unsigned short* __restrict__ cy, int pps)
{
    __shared__ float4 pts4[TILE * 8];
    float qv[QPL][32];
    float rq[QPL];
    int nx[QPL], ny[QPL];
    #pragma unroll
    for (int u = 0; u < QPL; ++u) {
        int q = blockIdx.x * (TPB * QPL) + threadIdx.x + u * TPB;
        load_query(qv[u], x, y, q);
        rq[u] = r[q];
        nx[u] = ny[u] = 0;
    }

    const int j0 = blockIdx.y * pps;
    for (int jt = j0; jt < j0 + pps; jt += TILE) {
        stage_tile(pts4, x, y, jt);
        __syncthreads();
        #pragma unroll 2
        for (int jj = 0; jj < TILE; ++jj) {
            float p[32];
            #pragma unroll
            for (int i = 0; i < 8; ++i) {
                float4 v = pts4[jj * 8 + i];   // wave-uniform broadcast
                p[4*i+0] = v.x; p[4*i+1] = v.y; p[4*i+2] = v.z; p[4*i+3] = v.w;
            }
            #pragma unroll
            for (int u = 0; u < QPL; ++u) {
                nx[u] += (cheb16(qv[u],      p)      <= rq[u]) ? 1 : 0;
                ny[u] += (cheb16(qv[u] + 16, p + 16) <= rq[u]) ? 1 : 0;
            }
        }
        __syncthreads();
    }
    #pragma unroll
    for (int u = 0; u < QPL; ++u) {
        int q = blockIdx.x * (TPB * QPL) + threadIdx.x + u * TPB;
        cx[(size_t)blockIdx.y * NPTS + q] = (unsigned short)nx[u];
        cy[(size_t)blockIdx.y * NPTS + q] = (unsigned short)ny[u];
    }
}

// ---------------------------------------------------------------------------
// K4: merge partial counts -> digamma(nx)+digamma(ny) per query (f64).
// ---------------------------------------------------------------------------
__global__ __launch_bounds__(TPM) void count_merge_kernel(
    const unsigned short* __restrict__ cx, const unsigned short* __restrict__ cy,
    double* __restrict__ dig, int S)
{
    const int q = blockIdx.x * TPM + threadIdx.x;
    int nx = 0, ny = 0;
    for (int s = 0; s < S; ++s) {
        nx += cx[(size_t)s * NPTS + q];
        ny += cy[(size_t)s * NPTS + q];
    }
    dig[q] = digamma_d((double)nx) + digamma_d((double)ny);
}

// ---------------------------------------------------------------------------
// K5: ans = psi(N) + psi(k) - mean(psi(nx)+psi(ny))
// (log/log2 terms of the reference cancel exactly in ans_x+ans_y-ans_xy)
// ---------------------------------------------------------------------------
__global__ __launch_bounds__(TPM) void final_kernel(
    const double* __restrict__ dig, float* __restrict__ out)
{
    __shared__ double sm[TPM];
    double s = 0.0;
    for (int i = threadIdx.x; i < NPTS; i += TPM) s += dig[i];
    sm[threadIdx.x] = s;
    __syncthreads();
    for (int w = TPM / 2; w > 0; w >>= 1) {
        if (threadIdx.x < w) sm[threadIdx.x] += sm[threadIdx.x + w];
        __syncthreads();
    }
    if (threadIdx.x == 0) {
        double ans = digamma_d((double)NPTS) + digamma_d(4.0) - sm[0] / (double)NPTS;
        out[0] = (float)ans;
    }
}

// ---------------------------------------------------------------------------
extern "C" void kernel_launch(void* const* d_in, const int* in_sizes, int n_in,
                              void* d_out, int out_size, void* d_ws, size_t ws_size,
                              hipStream_t stream)
{
    (void)in_sizes; (void)n_in; (void)out_size;
    const float* x = (const float*)d_in[0];
    const float* y = (const float*)d_in[1];
    float* out = (float*)d_out;

    // workspace: dig (NPTS f64) | r (NPTS f32) | part (S*NPTS float4) | cx,cy (S*NPTS u16 each)
    char* ws = (char*)d_ws;
    double* dig = (double*)ws;
    float*  r   = (float*)(ws + (size_t)NPTS * 8);
    char*   p0  = ws + (size_t)NPTS * 8 + (size_t)NPTS * 4 + 4; // +4 pad -> 16B-align part
    p0 = (char*)(((size_t)p0 + 15) & ~(size_t)15);

    auto need = [&](int S) {
        return (size_t)(p0 - ws) + (size_t)S * NPTS * 16 + (size_t)S * NPTS * 4;
    };
    int S = 128;
    while (S > 1 && need(S) > ws_size) S >>= 1;

    float4* part = (float4*)p0;
    unsigned short* cx = (unsigned short*)(p0 + (size_t)S * NPTS * 16);
    unsigned short* cy = cx + (size_t)S * NPTS;
    const int pps = NPTS / S;   // S<=128 -> pps>=64, multiple of TILE

    if (S >= 128) {
        // QPL=2: grid (16,128) = 2048 blocks, 8192 waves; half the LDS reads/pair
        dim3 gridP(NPTS / (TPB * 2), S);
        knn_part_kernel<2><<<gridP, TPB, 0, stream>>>(x, y, part, pps);
        knn_merge_kernel<<<NPTS / TPM, TPM, 0, stream>>>(part, r, S);
        count_part_kernel<2><<<gridP, TPB, 0, stream>>>(x, y, r, cx, cy, pps);
    } else {
        // fallback: R2-proven shape (QPL=1), still 8192 waves at S=64
        dim3 gridP(NPTS / TPB, S);
        knn_part_kernel<1><<<gridP, TPB, 0, stream>>>(x, y, part, pps);
        knn_merge_kernel<<<NPTS / TPM, TPM, 0, stream>>>(part, r, S);
        count_part_kernel<1><<<gridP, TPB, 0, stream>>>(x, y, r, cx, cy, pps);
    }
    count_merge_kernel<<<NPTS / TPM, TPM, 0, stream>>>(cx, cy, dig, S);
    final_kernel<<<1, TPM, 0, stream>>>(dig, out);
}